// Round 1
// baseline (197.249 us; speedup 1.0000x reference)
//
#include <hip/hip_runtime.h>

#define NSEQ 2048
#define DIM  512
#define KVBLK 32
#define NKT  64                    // 2048 / 32
#define TILEB 32768                // 32*512*2 bytes (bf16 tile)
#define SMEMB (4 * TILEB + 4096)   // K0,K1,V0,V1 + 4KB P-lds

typedef __bf16 bf16x8 __attribute__((ext_vector_type(8)));
typedef float  f32x4  __attribute__((ext_vector_type(4)));

__device__ __forceinline__ void gld16(const void* g, void* l) {
  __builtin_amdgcn_global_load_lds(
      (const __attribute__((address_space(1))) unsigned int*)g,
      (__attribute__((address_space(3))) unsigned int*)l, 16, 0, 0);
}

// ---------- pre-pass: K -> bf16, per-tile [32 rows][512 d], byte ^= ((row&7)<<4)
__global__ __launch_bounds__(256) void prep_k(const float* __restrict__ ks,
                                              char* __restrict__ kp) {
  int b = blockIdx.x >> 6, kt = blockIdx.x & 63;
  int t = threadIdx.x;
  const float* src = ks + ((size_t)(b * NSEQ + kt * KVBLK)) * DIM;
  char* dst = kp + ((size_t)(b * 64 + kt)) * TILEB;
#pragma unroll
  for (int i = 0; i < 8; ++i) {
    int c = t + i * 256;
    int row = c >> 6;
    int d0 = (c & 63) * 8;
    const float4* s4 = (const float4*)(src + row * DIM + d0);
    float4 x = s4[0], y = s4[1];
    bf16x8 h;
    h[0] = (__bf16)x.x; h[1] = (__bf16)x.y; h[2] = (__bf16)x.z; h[3] = (__bf16)x.w;
    h[4] = (__bf16)y.x; h[5] = (__bf16)y.y; h[6] = (__bf16)y.z; h[7] = (__bf16)y.w;
    *(bf16x8*)(dst + row * 1024 + ((d0 * 2) ^ ((row & 7) << 4))) = h;
  }
}

// ---------- pre-pass: V -> bf16 transposed per tile: Vt[d][kv],
// byte(d,kv) = (d>>1)*128 + ((((d&1)*64) + kv*2) ^ (((d>>1)&7)<<4))
__global__ __launch_bounds__(256) void prep_v(const float* __restrict__ vs,
                                              char* __restrict__ vtp) {
  __shared__ __align__(16) char lds[TILEB];
  int b = blockIdx.x >> 6, kt = blockIdx.x & 63;
  int t = threadIdx.x;
  const float* src = vs + ((size_t)(b * NSEQ + kt * KVBLK)) * DIM;
#pragma unroll
  for (int i = 0; i < 8; ++i) {
    int c = t + i * 256;
    int kv = c >> 6;
    int d0 = (c & 63) * 8;
    const float4* s4 = (const float4*)(src + kv * DIM + d0);
    float4 x = s4[0], y = s4[1];
    float vals[8] = {x.x, x.y, x.z, x.w, y.x, y.y, y.z, y.w};
#pragma unroll
    for (int j = 0; j < 8; ++j) {
      int d = d0 + j;
      int byte = (d >> 1) * 128 + (((((d & 1) * 64) + kv * 2)) ^ (((d >> 1) & 7) << 4));
      *(__bf16*)(lds + byte) = (__bf16)vals[j];
    }
  }
  __syncthreads();
  char* dst = vtp + ((size_t)(b * 64 + kt)) * TILEB;
#pragma unroll
  for (int i = 0; i < 8; ++i) {
    int c16 = t + i * 256;
    *(bf16x8*)(dst + c16 * 16) = *(const bf16x8*)(lds + c16 * 16);
  }
}

// ---------- main flash-attention kernel
__global__ __launch_bounds__(256, 1) void attn_main(
    const float* __restrict__ qs, const char* __restrict__ kp,
    const char* __restrict__ vtp, const float* __restrict__ scale,
    float* __restrict__ out) {
  extern __shared__ __align__(16) char smem[];
  int b  = blockIdx.x & 7;          // same batch -> same XCD (L2 locality)
  int qt = blockIdx.x >> 3;
  int tid = threadIdx.x;
  int w = tid >> 6, lane = tid & 63;
  int c = lane & 15, g = lane >> 4;
  int q0 = qt * 64 + w * 16;

  char* kbuf0 = smem;
  char* kbuf1 = smem + TILEB;
  char* vbuf0 = smem + 2 * TILEB;
  char* vbuf1 = smem + 3 * TILEB;
  char* plds  = smem + 4 * TILEB + w * 1024;

  float cc = 1.4426950408889634f / scale[0];   // log2(e)/scale folded into Q

  // Q fragments in registers: A-frag lane holds Q[q0+c][k*32 + g*8 .. +7]
  bf16x8 qf[16];
#pragma unroll
  for (int k = 0; k < 16; ++k) {
    int d = k * 32 + g * 8;
    const float4* p = (const float4*)(qs + ((size_t)(b * NSEQ + q0 + c)) * DIM + d);
    float4 x = p[0], y = p[1];
    float vals[8] = {x.x, x.y, x.z, x.w, y.x, y.y, y.z, y.w};
    bf16x8 h;
#pragma unroll
    for (int j = 0; j < 8; ++j) {
      float mlt = (d + j == 0) ? cc : -cc;     // Minkowski sign fold
      h[j] = (__bf16)(vals[j] * mlt);
    }
    qf[k] = h;
  }

  f32x4 acc[32];
#pragma unroll
  for (int i = 0; i < 32; ++i) acc[i] = (f32x4){0.f, 0.f, 0.f, 0.f};
  float mrow[4] = {-1e30f, -1e30f, -1e30f, -1e30f};

  const char* kpb = kp  + (size_t)b * 64 * TILEB;
  const char* vpb = vtp + (size_t)b * 64 * TILEB;

  // stage tile 0
#pragma unroll
  for (int i = 0; i < 8; ++i) {
    int o = (w * 512 + i * 64) * 16;
    gld16(kpb + o + lane * 16, kbuf0 + o);
    gld16(vpb + o + lane * 16, vbuf0 + o);
  }
  __syncthreads();

  // per-lane invariant LDS addresses
  const int vt_lane = (c >> 1) * 128 + (((((c & 1) * 64) + g * 16)) ^ (((c >> 1) & 7) << 4));
  const int pf_lane = vt_lane;  // P read uses same formula with q'=c, kv'=g*8

  for (int t = 0; t < NKT; ++t) {
    char* kb = (t & 1) ? kbuf1 : kbuf0;
    char* vb = (t & 1) ? vbuf1 : vbuf0;
    if (t + 1 < NKT) {
      char* kn = (t & 1) ? kbuf0 : kbuf1;
      char* vn = (t & 1) ? vbuf0 : vbuf1;
      const char* ksrc = kpb + (size_t)(t + 1) * TILEB;
      const char* vsrc = vpb + (size_t)(t + 1) * TILEB;
#pragma unroll
      for (int i = 0; i < 8; ++i) {
        int o = (w * 512 + i * 64) * 16;
        gld16(ksrc + o + lane * 16, kn + o);
        gld16(vsrc + o + lane * 16, vn + o);
      }
    }

    // ---- QK^T: S[q][kv], two 16-col tiles
    f32x4 s0 = {0.f, 0.f, 0.f, 0.f}, s1 = {0.f, 0.f, 0.f, 0.f};
    const char* kr0 = kb + c * 1024;
#pragma unroll
    for (int k = 0; k < 16; ++k) {
      int bir = ((k * 64 + g * 16) ^ ((c & 7) << 4));
      bf16x8 kf0 = *(const bf16x8*)(kr0 + bir);
      bf16x8 kf1 = *(const bf16x8*)(kr0 + 16384 + bir);
      s0 = __builtin_amdgcn_mfma_f32_16x16x32_bf16(qf[k], kf0, s0, 0, 0, 0);
      s1 = __builtin_amdgcn_mfma_f32_16x16x32_bf16(qf[k], kf1, s1, 0, 0, 0);
    }

    // ---- online softmax (log2 domain, exp-sum not needed: normalization cancels)
    float mt[4];
    bool grow = false;
#pragma unroll
    for (int r = 0; r < 4; ++r) {
      float v = fmaxf(s0[r], s1[r]);
      v = fmaxf(v, __shfl_xor(v, 1));
      v = fmaxf(v, __shfl_xor(v, 2));
      v = fmaxf(v, __shfl_xor(v, 4));
      v = fmaxf(v, __shfl_xor(v, 8));
      mt[r] = v;
      grow = grow || (v > mrow[r] + 11.0f);   // defer-max threshold (2^11 headroom)
    }
    if (__any(grow)) {
      float f[4];
#pragma unroll
      for (int r = 0; r < 4; ++r) {
        float mn = fmaxf(mrow[r], mt[r]);
        f[r] = exp2f(mrow[r] - mn);
        mrow[r] = mn;
      }
#pragma unroll
      for (int i = 0; i < 32; ++i) {
        acc[i][0] *= f[0]; acc[i][1] *= f[1]; acc[i][2] *= f[2]; acc[i][3] *= f[3];
      }
    }
    float p0[4], p1[4];
#pragma unroll
    for (int r = 0; r < 4; ++r) {
      p0[r] = exp2f(s0[r] - mrow[r]);
      p1[r] = exp2f(s1[r] - mrow[r]);
    }

    // ---- P: C-layout -> A-layout via per-wave LDS roundtrip
#pragma unroll
    for (int r = 0; r < 4; ++r) {
      int q = 4 * g + r;
      int rb = (q >> 1) * 128;
      int sw = ((q >> 1) & 7) << 4;
      *(__bf16*)(plds + rb + ((((q & 1) * 64) + c * 2) ^ sw))        = (__bf16)p0[r];
      *(__bf16*)(plds + rb + ((((q & 1) * 64) + (16 + c) * 2) ^ sw)) = (__bf16)p1[r];
    }
    bf16x8 pf = *(const bf16x8*)(plds + pf_lane);

    // ---- PV: O[q][d] += P * V   (Vt LDS: contiguous kv per lane)
    const char* vr = vb + vt_lane;
#pragma unroll
    for (int dt = 0; dt < 32; ++dt) {
      bf16x8 vf = *(const bf16x8*)(vr + dt * 1024);
      acc[dt] = __builtin_amdgcn_mfma_f32_16x16x32_bf16(pf, vf, acc[dt], 0, 0, 0);
    }
    __syncthreads();
  }

  // ---- epilogue: Lorentz normalization (exp-sum l cancels; EPS clamp preserved)
#pragma unroll
  for (int r = 0; r < 4; ++r) {
    float ss = 0.f;
#pragma unroll
    for (int dt = 0; dt < 32; ++dt) ss += acc[dt][r] * acc[dt][r];
    ss += __shfl_xor(ss, 1);
    ss += __shfl_xor(ss, 2);
    ss += __shfl_xor(ss, 4);
    ss += __shfl_xor(ss, 8);
    float a0 = __shfl(acc[0][r], lane & 48);   // lane with c==0 holds O[q][0]
    float d2 = fabsf(2.f * a0 * a0 - ss);
    d2 = fmaxf(d2, 1e-8f);
    float inv = rsqrtf(d2);
    float* orow = out + ((size_t)(b * NSEQ + q0 + 4 * g + r)) * DIM + c;
#pragma unroll
    for (int dt = 0; dt < 32; ++dt) orow[dt * 16] = acc[dt][r] * inv;
  }
}

extern "C" void kernel_launch(void* const* d_in, const int* in_sizes, int n_in,
                              void* d_out, int out_size, void* d_ws, size_t ws_size,
                              hipStream_t stream) {
  (void)in_sizes; (void)n_in; (void)out_size;
  const float* qs = (const float*)d_in[0];
  const float* ks = (const float*)d_in[1];
  const float* vs = (const float*)d_in[2];
  const float* scale = (const float*)d_in[3];
  // d_in[4] (bias) is uniform across the softmax axis -> softmax-invariant -> unused
  float* out = (float*)d_out;

  size_t need = (size_t)2 * 8 * 64 * TILEB;   // 33.5 MB
  if (ws_size < need) return;                  // loud failure signal if ws too small
  char* kp  = (char*)d_ws;
  char* vtp = (char*)d_ws + (size_t)8 * 64 * TILEB;

  hipFuncSetAttribute((const void*)attn_main,
                      hipFuncAttributeMaxDynamicSharedMemorySize, SMEMB);

  prep_k<<<512, 256, 0, stream>>>(ks, kp);
  prep_v<<<512, 256, 0, stream>>>(vs, vtp);
  attn_main<<<256, 256, SMEMB, stream>>>(qs, kp, vtp, scale, out);
}

// Round 2
// 170.958 us; speedup vs baseline: 1.1538x; 1.1538x over previous
//
#include <hip/hip_runtime.h>

#define NSEQ 2048
#define DIM  512
#define KVBLK 32
#define NKT  64                    // 2048 / 32
#define TILEB 32768                // 32*512*2 bytes (bf16 tile)
#define P_OFF  131072              // after K0,K1,V0,V1
#define M_OFF  135168              // after P (4KB)
#define SS_OFF 135168              // epilogue reuse of m_lds
#define IV_OFF 135424
#define SMEMB  135680

typedef __bf16 bf16x8 __attribute__((ext_vector_type(8)));
typedef float  f32x4  __attribute__((ext_vector_type(4)));

__device__ __forceinline__ void gld16(const void* g, void* l) {
  __builtin_amdgcn_global_load_lds(
      (const __attribute__((address_space(1))) unsigned int*)g,
      (__attribute__((address_space(3))) unsigned int*)l, 16, 0, 0);
}

// ---------- pre-pass: K -> bf16, per-tile [32 rows][512 d], byte ^= ((row&7)<<4)
__global__ __launch_bounds__(256) void prep_k(const float* __restrict__ ks,
                                              char* __restrict__ kp) {
  int b = blockIdx.x >> 6, kt = blockIdx.x & 63;
  int t = threadIdx.x;
  const float* src = ks + ((size_t)(b * NSEQ + kt * KVBLK)) * DIM;
  char* dst = kp + ((size_t)(b * 64 + kt)) * TILEB;
#pragma unroll
  for (int i = 0; i < 8; ++i) {
    int c = t + i * 256;
    int row = c >> 6;
    int d0 = (c & 63) * 8;
    const float4* s4 = (const float4*)(src + row * DIM + d0);
    float4 x = s4[0], y = s4[1];
    bf16x8 h;
    h[0] = (__bf16)x.x; h[1] = (__bf16)x.y; h[2] = (__bf16)x.z; h[3] = (__bf16)x.w;
    h[4] = (__bf16)y.x; h[5] = (__bf16)y.y; h[6] = (__bf16)y.z; h[7] = (__bf16)y.w;
    *(bf16x8*)(dst + row * 1024 + ((d0 * 2) ^ ((row & 7) << 4))) = h;
  }
}

// ---------- pre-pass: V -> bf16 transposed per tile: Vt[d][kv],
// byte(d,kv) = (d>>1)*128 + ((((d&1)*64) + kv*2) ^ (((d>>1)&7)<<4))
__global__ __launch_bounds__(256) void prep_v(const float* __restrict__ vs,
                                              char* __restrict__ vtp) {
  __shared__ __align__(16) char lds[TILEB];
  int b = blockIdx.x >> 6, kt = blockIdx.x & 63;
  int t = threadIdx.x;
  const float* src = vs + ((size_t)(b * NSEQ + kt * KVBLK)) * DIM;
#pragma unroll
  for (int i = 0; i < 8; ++i) {
    int c = t + i * 256;
    int kv = c >> 6;
    int d0 = (c & 63) * 8;
    const float4* s4 = (const float4*)(src + kv * DIM + d0);
    float4 x = s4[0], y = s4[1];
    float vals[8] = {x.x, x.y, x.z, x.w, y.x, y.y, y.z, y.w};
#pragma unroll
    for (int j = 0; j < 8; ++j) {
      int d = d0 + j;
      int byte = (d >> 1) * 128 + (((((d & 1) * 64) + kv * 2)) ^ (((d >> 1) & 7) << 4));
      *(__bf16*)(lds + byte) = (__bf16)vals[j];
    }
  }
  __syncthreads();
  char* dst = vtp + ((size_t)(b * 64 + kt)) * TILEB;
#pragma unroll
  for (int i = 0; i < 8; ++i) {
    int c16 = t + i * 256;
    *(bf16x8*)(dst + c16 * 16) = *(const bf16x8*)(lds + c16 * 16);
  }
}

// ---------- main: 8 waves = (wq 0..3) x (wr 0..1); wr splits QK kv-halves and PV d-halves
__global__ __launch_bounds__(512, 2) void attn_main(
    const float* __restrict__ qs, const char* __restrict__ kp,
    const char* __restrict__ vtp, const float* __restrict__ scale,
    float* __restrict__ out) {
  extern __shared__ __align__(16) char smem[];
  int b  = blockIdx.x & 7;          // same batch -> same XCD (L2 locality)
  int qt = blockIdx.x >> 3;
  int tid = threadIdx.x;
  int w = tid >> 6, lane = tid & 63;
  int wq = w >> 1, wr = w & 1;
  int c = lane & 15, g = lane >> 4;
  int q0 = qt * 64 + wq * 16;

  char* kbuf0 = smem;
  char* kbuf1 = smem + TILEB;
  char* vbuf0 = smem + 2 * TILEB;
  char* vbuf1 = smem + 3 * TILEB;
  char* plds  = smem + P_OFF + wq * 1024;
  float* ml_own = (float*)(smem + M_OFF) + (wq * 2 + wr) * 16;
  float* ml_par = (float*)(smem + M_OFF) + (wq * 2 + (wr ^ 1)) * 16;

  float cc = 1.4426950408889634f / scale[0];   // log2(e)/scale folded into Q

  // Q fragments: lane holds Q[q0+c][k*32 + g*8 .. +7]
  bf16x8 qf[16];
#pragma unroll
  for (int k = 0; k < 16; ++k) {
    int d = k * 32 + g * 8;
    const float4* p = (const float4*)(qs + ((size_t)(b * NSEQ + q0 + c)) * DIM + d);
    float4 x = p[0], y = p[1];
    float vals[8] = {x.x, x.y, x.z, x.w, y.x, y.y, y.z, y.w};
    bf16x8 h;
#pragma unroll
    for (int j = 0; j < 8; ++j) {
      float mlt = (d + j == 0) ? cc : -cc;     // Minkowski sign fold
      h[j] = (__bf16)(vals[j] * mlt);
    }
    qf[k] = h;
  }

  f32x4 acc[16];                                // 16q x 256d (own d-half)
#pragma unroll
  for (int i = 0; i < 16; ++i) acc[i] = (f32x4){0.f, 0.f, 0.f, 0.f};
  float mrow[4] = {-1e30f, -1e30f, -1e30f, -1e30f};

  const char* kpb = kp  + (size_t)b * 64 * TILEB;
  const char* vpb = vtp + (size_t)b * 64 * TILEB;

  // stage tile 0 (K and V), 8 waves cooperate
#pragma unroll
  for (int i = 0; i < 4; ++i) {
    int o = w * 4096 + i * 1024;
    gld16(kpb + o + lane * 16, kbuf0 + o);
    gld16(vpb + o + lane * 16, vbuf0 + o);
  }
  __syncthreads();

  const int vt_lane = (c >> 1) * 128 + (((((c & 1) * 64) + g * 16)) ^ (((c >> 1) & 7) << 4));

  for (int t = 0; t < NKT; ++t) {
    char* kb = (t & 1) ? kbuf1 : kbuf0;
    char* vb = (t & 1) ? vbuf1 : vbuf0;
    char* kn = (t & 1) ? kbuf0 : kbuf1;
    char* vn = (t & 1) ? vbuf0 : vbuf1;

    // stage K(t+1) early: drains at bar1, covered by QK
    if (t + 1 < NKT) {
      const char* ksrc = kpb + (size_t)(t + 1) * TILEB;
#pragma unroll
      for (int i = 0; i < 4; ++i) {
        int o = w * 4096 + i * 1024;
        gld16(ksrc + o + lane * 16, kn + o);
      }
    }

    // ---- QK^T: S[16q x 16kv], own kv-half (rows wr*16 + c)
    __builtin_amdgcn_s_setprio(1);
    f32x4 s = {0.f, 0.f, 0.f, 0.f};
    const char* kr0 = kb + (wr * 16 + c) * 1024;
#pragma unroll
    for (int k = 0; k < 16; ++k) {
      int bir = ((k * 64 + g * 16) ^ ((c & 7) << 4));
      bf16x8 kf = *(const bf16x8*)(kr0 + bir);
      s = __builtin_amdgcn_mfma_f32_16x16x32_bf16(qf[k], kf, s, 0, 0, 0);
    }
    __builtin_amdgcn_s_setprio(0);

    // ---- own-half row max
    float mt[4];
#pragma unroll
    for (int r = 0; r < 4; ++r) {
      float v = s[r];
      v = fmaxf(v, __shfl_xor(v, 1));
      v = fmaxf(v, __shfl_xor(v, 2));
      v = fmaxf(v, __shfl_xor(v, 4));
      v = fmaxf(v, __shfl_xor(v, 8));
      mt[r] = v;
    }
    if (c == 0) {
#pragma unroll
      for (int r = 0; r < 4; ++r) ml_own[4 * g + r] = mt[r];
    }
    __syncthreads();                                   // bar1: m-halves + K(t+1) ready

    // ---- shared max + defer-max rescale
    bool grow = false;
#pragma unroll
    for (int r = 0; r < 4; ++r) {
      mt[r] = fmaxf(mt[r], ml_par[4 * g + r]);
      grow = grow || (mt[r] > mrow[r] + 11.0f);        // 2^11 headroom
    }
    if (__any(grow)) {
      float f[4];
#pragma unroll
      for (int r = 0; r < 4; ++r) {
        float mn = fmaxf(mrow[r], mt[r]);
        f[r] = exp2f(mrow[r] - mn);
        mrow[r] = mn;
      }
#pragma unroll
      for (int i = 0; i < 16; ++i) {
        acc[i][0] *= f[0]; acc[i][1] *= f[1]; acc[i][2] *= f[2]; acc[i][3] *= f[3];
      }
    }

    // ---- P write (own 16 cols at wr*16 + c)
#pragma unroll
    for (int r = 0; r < 4; ++r) {
      float pv = exp2f(s[r] - mrow[r]);
      int q = 4 * g + r;
      int byte = (q >> 1) * 128 +
                 (((((q & 1) * 64) + (wr * 16 + c) * 2)) ^ (((q >> 1) & 7) << 4));
      *(__bf16*)(plds + byte) = (__bf16)pv;
    }
    __syncthreads();                                   // bar2: full P ready

    // stage V(t+1) late: drains at bar3, covered by PV
    if (t + 1 < NKT) {
      const char* vsrc = vpb + (size_t)(t + 1) * TILEB;
#pragma unroll
      for (int i = 0; i < 4; ++i) {
        int o = w * 4096 + i * 1024;
        gld16(vsrc + o + lane * 16, vn + o);
      }
    }

    // ---- PV: own d-half (wr*256 .. +255), full 32 kv, K=32
    bf16x8 pf = *(const bf16x8*)(plds + vt_lane);
    __builtin_amdgcn_s_setprio(1);
    const char* vr = vb + wr * 16384 + vt_lane;
#pragma unroll
    for (int dtl = 0; dtl < 16; ++dtl) {
      bf16x8 vf = *(const bf16x8*)(vr + dtl * 1024);
      acc[dtl] = __builtin_amdgcn_mfma_f32_16x16x32_bf16(pf, vf, acc[dtl], 0, 0, 0);
    }
    __builtin_amdgcn_s_setprio(0);
    __syncthreads();                                   // bar3: PV reads done, V(t+1) ready
  }

  // ---- epilogue: Lorentz normalization across the wr pair
  float ps[4];
#pragma unroll
  for (int r = 0; r < 4; ++r) {
    float ss = 0.f;
#pragma unroll
    for (int dtl = 0; dtl < 16; ++dtl) ss += acc[dtl][r] * acc[dtl][r];
    ss += __shfl_xor(ss, 1);
    ss += __shfl_xor(ss, 2);
    ss += __shfl_xor(ss, 4);
    ss += __shfl_xor(ss, 8);
    ps[r] = ss;
  }
  float* sl = (float*)(smem + SS_OFF) + wq * 16;
  float* il = (float*)(smem + IV_OFF) + wq * 16;
  if (wr == 1 && c == 0) {
#pragma unroll
    for (int r = 0; r < 4; ++r) sl[4 * g + r] = ps[r];
  }
  __syncthreads();
  if (wr == 0) {
#pragma unroll
    for (int r = 0; r < 4; ++r) {
      float ssf = ps[r] + sl[4 * g + r];
      float a0 = __shfl(acc[0][r], lane & 48);         // lane c==0: O[q][0]
      float d2 = fabsf(2.f * a0 * a0 - ssf);
      float inv = rsqrtf(fmaxf(d2, 1e-8f));
      if (c == 0) il[4 * g + r] = inv;
      float* orow = out + ((size_t)(b * NSEQ + q0 + 4 * g + r)) * DIM + c;
#pragma unroll
      for (int dtl = 0; dtl < 16; ++dtl) orow[dtl * 16] = acc[dtl][r] * inv;
    }
  }
  __syncthreads();
  if (wr == 1) {
#pragma unroll
    for (int r = 0; r < 4; ++r) {
      float inv = il[4 * g + r];
      float* orow = out + ((size_t)(b * NSEQ + q0 + 4 * g + r)) * DIM + 256 + c;
#pragma unroll
      for (int dtl = 0; dtl < 16; ++dtl) orow[dtl * 16] = acc[dtl][r] * inv;
    }
  }
}

extern "C" void kernel_launch(void* const* d_in, const int* in_sizes, int n_in,
                              void* d_out, int out_size, void* d_ws, size_t ws_size,
                              hipStream_t stream) {
  (void)in_sizes; (void)n_in; (void)out_size;
  const float* qs = (const float*)d_in[0];
  const float* ks = (const float*)d_in[1];
  const float* vs = (const float*)d_in[2];
  const float* scale = (const float*)d_in[3];
  // d_in[4] (bias) is uniform across the softmax axis -> softmax-invariant -> unused
  float* out = (float*)d_out;

  size_t need = (size_t)2 * 8 * 64 * TILEB;   // 33.5 MB
  if (ws_size < need) return;
  char* kp  = (char*)d_ws;
  char* vtp = (char*)d_ws + (size_t)8 * 64 * TILEB;

  hipFuncSetAttribute((const void*)attn_main,
                      hipFuncAttributeMaxDynamicSharedMemorySize, SMEMB);

  prep_k<<<512, 256, 0, stream>>>(ks, kp);
  prep_v<<<512, 256, 0, stream>>>(vs, vtp);
  attn_main<<<256, 512, SMEMB, stream>>>(qs, kp, vtp, scale, out);
}

// Round 4
// 167.303 us; speedup vs baseline: 1.1790x; 1.0218x over previous
//
#include <hip/hip_runtime.h>

#define NSEQ 2048
#define DIM  512
#define KVBLK 32
#define NKT  64                    // 2048 / 32
#define TILEB 32768                // 32*512*2 bytes (bf16 tile)
#define SMEMB (4 * TILEB + 4096)   // K0,K1,V0,V1 + 4KB per-wave P-lds

typedef __bf16 bf16x8 __attribute__((ext_vector_type(8)));
typedef float  f32x4  __attribute__((ext_vector_type(4)));

__device__ __forceinline__ void gld16(const void* g, void* l) {
  __builtin_amdgcn_global_load_lds(
      (const __attribute__((address_space(1))) unsigned int*)g,
      (__attribute__((address_space(3))) unsigned int*)l, 16, 0, 0);
}

// ---------- pre-pass: K -> bf16, per-tile [32 kv][512 d], byte ^= ((row&7)<<4)
__global__ __launch_bounds__(256) void prep_k(const float* __restrict__ ks,
                                              char* __restrict__ kp) {
  int b = blockIdx.x >> 6, kt = blockIdx.x & 63;
  int t = threadIdx.x;
  const float* src = ks + ((size_t)(b * NSEQ + kt * KVBLK)) * DIM;
  char* dst = kp + ((size_t)(b * 64 + kt)) * TILEB;
#pragma unroll
  for (int i = 0; i < 8; ++i) {
    int c = t + i * 256;
    int row = c >> 6;
    int d0 = (c & 63) * 8;
    const float4* s4 = (const float4*)(src + row * DIM + d0);
    float4 x = s4[0], y = s4[1];
    bf16x8 h;
    h[0] = (__bf16)x.x; h[1] = (__bf16)x.y; h[2] = (__bf16)x.z; h[3] = (__bf16)x.w;
    h[4] = (__bf16)y.x; h[5] = (__bf16)y.y; h[6] = (__bf16)y.z; h[7] = (__bf16)y.w;
    *(bf16x8*)(dst + row * 1024 + ((d0 * 2) ^ ((row & 7) << 4))) = h;
  }
}

// ---------- pre-pass: V -> bf16 transposed per tile (R1-verified layout):
// byte(d,kv) = (d>>1)*128 + ((((d&1)*64) + kv*2) ^ (((d>>1)&7)<<4))
__global__ __launch_bounds__(256) void prep_v(const float* __restrict__ vs,
                                              char* __restrict__ vtp) {
  __shared__ __align__(16) char lds[TILEB];
  int b = blockIdx.x >> 6, kt = blockIdx.x & 63;
  int t = threadIdx.x;
  const float* src = vs + ((size_t)(b * NSEQ + kt * KVBLK)) * DIM;
#pragma unroll
  for (int i = 0; i < 8; ++i) {
    int c = t + i * 256;
    int kv = c >> 6;
    int d0 = (c & 63) * 8;
    const float4* s4 = (const float4*)(src + kv * DIM + d0);
    float4 x = s4[0], y = s4[1];
    float vals[8] = {x.x, x.y, x.z, x.w, y.x, y.y, y.z, y.w};
#pragma unroll
    for (int j = 0; j < 8; ++j) {
      int d = d0 + j;
      int byte = (d >> 1) * 128 + (((((d & 1) * 64) + kv * 2)) ^ (((d >> 1) & 7) << 4));
      *(__bf16*)(lds + byte) = (__bf16)vals[j];
    }
  }
  __syncthreads();
  char* dst = vtp + ((size_t)(b * 64 + kt)) * TILEB;
#pragma unroll
  for (int i = 0; i < 8; ++i) {
    int c16 = t + i * 256;
    *(bf16x8*)(dst + c16 * 16) = *(const bf16x8*)(lds + c16 * 16);
  }
}

// ---------- main: 4 independent waves x 16q, swapped-QK, lane-local softmax,
// P via per-wave LDS roundtrip (R1-verified layout/read)
__global__ __launch_bounds__(256) void attn_main(
    const float* __restrict__ qs, const char* __restrict__ kp,
    const char* __restrict__ vtp, const float* __restrict__ scale,
    float* __restrict__ out) {
  extern __shared__ __align__(16) char smem[];
  int b  = blockIdx.x & 7;          // batch -> XCD (L2 locality)
  int qt = blockIdx.x >> 3;
  int tid = threadIdx.x;
  int w = tid >> 6, lane = tid & 63;
  int c = lane & 15, g = lane >> 4;
  int q0 = qt * 64 + w * 16;

  char* kb0 = smem;
  char* kb1 = smem + TILEB;
  char* vb0 = smem + 2 * TILEB;
  char* vb1 = smem + 3 * TILEB;
  char* plds = smem + 4 * TILEB + w * 1024;

  float cc = 1.4426950408889634f / scale[0];   // log2(e)/scale folded into Q

  // Q fragments (B-operand for swapped QK; lane holds Q[q=c][k*32+g*8..+7])
  bf16x8 qf[16];
#pragma unroll
  for (int k = 0; k < 16; ++k) {
    int d = k * 32 + g * 8;
    const float4* p = (const float4*)(qs + ((size_t)(b * NSEQ + q0 + c)) * DIM + d);
    float4 x = p[0], y = p[1];
    float vals[8] = {x.x, x.y, x.z, x.w, y.x, y.y, y.z, y.w};
    bf16x8 h;
#pragma unroll
    for (int j = 0; j < 8; ++j) {
      float mlt = (d + j == 0) ? cc : -cc;     // Minkowski sign fold
      h[j] = (__bf16)(vals[j] * mlt);
    }
    qf[k] = h;
  }

  f32x4 acc[32];
#pragma unroll
  for (int i = 0; i < 32; ++i) acc[i] = (f32x4){0.f, 0.f, 0.f, 0.f};
  float mrow = -1e30f;               // running max for q=c (lane-local)

  const char* kpb = kp  + (size_t)b * 64 * TILEB;
  const char* vpb = vtp + (size_t)b * 64 * TILEB;

  // prologue: stage tile 0
#pragma unroll
  for (int i = 0; i < 8; ++i) {
    int o = tid * 16 + i * 4096;
    gld16(kpb + o, kb0 + o);
    gld16(vpb + o, vb0 + o);
  }
  __syncthreads();

  const int csw = (c & 7) << 4;                // K swizzle term
  const int vt_lane = (c >> 1) * 128 +
      (((((c & 1) * 64) + g * 16)) ^ (((c >> 1) & 7) << 4));  // V/P A-frag read
  // P write-side (q = c fixed per lane)
  const int qb = (c >> 1) * 128;
  const int qh = (c & 1) * 64;
  const int qx = ((c >> 1) & 7) << 4;

  for (int t = 0; t < NKT; ++t) {
    char* kb = (t & 1) ? kb1 : kb0;
    char* vb = (t & 1) ? vb1 : vb0;
    if (t + 1 < NKT) {
      char* kn = (t & 1) ? kb0 : kb1;
      char* vn = (t & 1) ? vb0 : vb1;
      const char* ksrc = kpb + (size_t)(t + 1) * TILEB;
      const char* vsrc = vpb + (size_t)(t + 1) * TILEB;
#pragma unroll
      for (int i = 0; i < 8; ++i) {
        int o = tid * 16 + i * 4096;
        gld16(ksrc + o, kn + o);
        gld16(vsrc + o, vn + o);
      }
    }

    // ---- swapped QK^T: lane (c,g) reg r = S[q=c][kv=4g+r] (lo) / 16+4g+r (hi)
    f32x4 sa0 = {0.f,0.f,0.f,0.f}, sb0 = {0.f,0.f,0.f,0.f};
    f32x4 sa1 = {0.f,0.f,0.f,0.f}, sb1 = {0.f,0.f,0.f,0.f};
    const char* krl = kb + c * 1024;          // kv = c      (lo half)
    const char* krh = krl + 16 * 1024;        // kv = 16 + c (hi half)
#pragma unroll
    for (int k = 0; k < 16; ++k) {
      int bir = (k * 64 + g * 16) ^ csw;
      bf16x8 kfl = *(const bf16x8*)(krl + bir);
      bf16x8 kfh = *(const bf16x8*)(krh + bir);
      if (k & 1) {
        sb0 = __builtin_amdgcn_mfma_f32_16x16x32_bf16(kfl, qf[k], sb0, 0, 0, 0);
        sb1 = __builtin_amdgcn_mfma_f32_16x16x32_bf16(kfh, qf[k], sb1, 0, 0, 0);
      } else {
        sa0 = __builtin_amdgcn_mfma_f32_16x16x32_bf16(kfl, qf[k], sa0, 0, 0, 0);
        sa1 = __builtin_amdgcn_mfma_f32_16x16x32_bf16(kfh, qf[k], sa1, 0, 0, 0);
      }
    }
    f32x4 sl = sa0 + sb0;                     // kv 4g+r
    f32x4 sh = sa1 + sb1;                     // kv 16+4g+r

    // ---- softmax (lane-local row q=c; reduce over g only)
    float mm = fmaxf(fmaxf(fmaxf(sl[0], sl[1]), fmaxf(sl[2], sl[3])),
                     fmaxf(fmaxf(sh[0], sh[1]), fmaxf(sh[2], sh[3])));
    mm = fmaxf(mm, __shfl_xor(mm, 16));
    mm = fmaxf(mm, __shfl_xor(mm, 32));
    if (__any(mm > mrow + 11.0f)) {          // defer-max (2^11 headroom)
      float mn = fmaxf(mrow, mm);
      float f = exp2f(mrow - mn);
      mrow = mn;
      float f0 = __shfl(f, 4 * g + 0), f1 = __shfl(f, 4 * g + 1);
      float f2 = __shfl(f, 4 * g + 2), f3 = __shfl(f, 4 * g + 3);
#pragma unroll
      for (int i = 0; i < 32; ++i) {
        acc[i][0] *= f0; acc[i][1] *= f1; acc[i][2] *= f2; acc[i][3] *= f3;
      }
    }

    // ---- P write (transposed-S source): q=c, kv = 4g+r and 16+4g+r
#pragma unroll
    for (int r = 0; r < 4; ++r) {
      float pvl = exp2f(sl[r] - mrow);
      float pvh = exp2f(sh[r] - mrow);
      int kvl = 4 * g + r;
      *(__bf16*)(plds + qb + ((qh + kvl * 2) ^ qx))        = (__bf16)pvl;
      *(__bf16*)(plds + qb + ((qh + (16 + kvl) * 2) ^ qx)) = (__bf16)pvh;
    }
    bf16x8 pf = *(const bf16x8*)(plds + vt_lane);   // P[q=c][kv=8g..8g+7]

    // ---- PV: O[q][d] += P . V  (B-frag: V[kv 8g..8g+7][d=16dtl+c])
    const char* vr = vb + vt_lane;
#pragma unroll
    for (int dtl = 0; dtl < 32; ++dtl) {
      bf16x8 vf = *(const bf16x8*)(vr + dtl * 1024);
      acc[dtl] = __builtin_amdgcn_mfma_f32_16x16x32_bf16(pf, vf, acc[dtl], 0, 0, 0);
    }
    __syncthreads();   // next tile staged; all waves done reading current buffers
  }

  // ---- epilogue: Lorentz normalization (softmax denom cancels; EPS preserved)
#pragma unroll
  for (int r = 0; r < 4; ++r) {
    float ss = 0.f;
#pragma unroll
    for (int dtl = 0; dtl < 32; ++dtl) ss += acc[dtl][r] * acc[dtl][r];
    ss += __shfl_xor(ss, 1);
    ss += __shfl_xor(ss, 2);
    ss += __shfl_xor(ss, 4);
    ss += __shfl_xor(ss, 8);
    float a0 = __shfl(acc[0][r], lane & 48);   // lane c==0 holds O[q][0]
    float d2 = fabsf(2.f * a0 * a0 - ss);
    float inv = rsqrtf(fmaxf(d2, 1e-8f));
    float* orow = out + ((size_t)(b * NSEQ + q0 + 4 * g + r)) * DIM + c;
#pragma unroll
    for (int dtl = 0; dtl < 32; ++dtl) orow[dtl * 16] = acc[dtl][r] * inv;
  }
}

extern "C" void kernel_launch(void* const* d_in, const int* in_sizes, int n_in,
                              void* d_out, int out_size, void* d_ws, size_t ws_size,
                              hipStream_t stream) {
  (void)in_sizes; (void)n_in; (void)out_size;
  const float* qs = (const float*)d_in[0];
  const float* ks = (const float*)d_in[1];
  const float* vs = (const float*)d_in[2];
  const float* scale = (const float*)d_in[3];
  // d_in[4] (bias) is uniform across softmax axis -> invariant -> unused
  float* out = (float*)d_out;

  size_t need = (size_t)2 * 8 * 64 * TILEB;   // 33.5 MB
  if (ws_size < need) return;
  char* kp  = (char*)d_ws;
  char* vtp = (char*)d_ws + (size_t)8 * 64 * TILEB;

  hipFuncSetAttribute((const void*)attn_main,
                      hipFuncAttributeMaxDynamicSharedMemorySize, SMEMB);

  prep_k<<<512, 256, 0, stream>>>(ks, kp);
  prep_v<<<512, 256, 0, stream>>>(vs, vtp);
  attn_main<<<256, 256, SMEMB, stream>>>(qs, kp, vtp, scale, out);
}

// Round 5
// 154.934 us; speedup vs baseline: 1.2731x; 1.0798x over previous
//
#include <hip/hip_runtime.h>

#define NSEQ 2048
#define DIM  512
#define KVBLK 32
#define NKT  64                    // 2048 / 32
#define TILEB 32768                // 32*512*2 bytes (bf16 tile)
#define SMEMB (4 * TILEB + 4096)   // K0,K1,V0,V1 + 4KB per-wave P-lds

typedef __bf16 bf16x8 __attribute__((ext_vector_type(8)));
typedef float  f32x4  __attribute__((ext_vector_type(4)));

__device__ __forceinline__ void gld16(const void* g, void* l) {
  __builtin_amdgcn_global_load_lds(
      (const __attribute__((address_space(1))) unsigned int*)g,
      (__attribute__((address_space(3))) unsigned int*)l, 16, 0, 0);
}

// ---------- pre-pass: K -> bf16, per-tile [32 kv][512 d], byte ^= ((row&7)<<4)
__global__ __launch_bounds__(256) void prep_k(const float* __restrict__ ks,
                                              char* __restrict__ kp) {
  int b = blockIdx.x >> 6, kt = blockIdx.x & 63;
  int t = threadIdx.x;
  const float* src = ks + ((size_t)(b * NSEQ + kt * KVBLK)) * DIM;
  char* dst = kp + ((size_t)(b * 64 + kt)) * TILEB;
#pragma unroll
  for (int i = 0; i < 8; ++i) {
    int c = t + i * 256;
    int row = c >> 6;
    int d0 = (c & 63) * 8;
    const float4* s4 = (const float4*)(src + row * DIM + d0);
    float4 x = s4[0], y = s4[1];
    bf16x8 h;
    h[0] = (__bf16)x.x; h[1] = (__bf16)x.y; h[2] = (__bf16)x.z; h[3] = (__bf16)x.w;
    h[4] = (__bf16)y.x; h[5] = (__bf16)y.y; h[6] = (__bf16)y.z; h[7] = (__bf16)y.w;
    *(bf16x8*)(dst + row * 1024 + ((d0 * 2) ^ ((row & 7) << 4))) = h;
  }
}

// ---------- pre-pass: V -> bf16 transposed per tile (R1-verified layout):
// byte(d,kv) = (d>>1)*128 + ((((d&1)*64) + kv*2) ^ (((d>>1)&7)<<4))
__global__ __launch_bounds__(256) void prep_v(const float* __restrict__ vs,
                                              char* __restrict__ vtp) {
  __shared__ __align__(16) char lds[TILEB];
  int b = blockIdx.x >> 6, kt = blockIdx.x & 63;
  int t = threadIdx.x;
  const float* src = vs + ((size_t)(b * NSEQ + kt * KVBLK)) * DIM;
#pragma unroll
  for (int i = 0; i < 8; ++i) {
    int c = t + i * 256;
    int kv = c >> 6;
    int d0 = (c & 63) * 8;
    const float4* s4 = (const float4*)(src + kv * DIM + d0);
    float4 x = s4[0], y = s4[1];
    float vals[8] = {x.x, x.y, x.z, x.w, y.x, y.y, y.z, y.w};
#pragma unroll
    for (int j = 0; j < 8; ++j) {
      int d = d0 + j;
      int byte = (d >> 1) * 128 + (((((d & 1) * 64) + kv * 2)) ^ (((d >> 1) & 7) << 4));
      *(__bf16*)(lds + byte) = (__bf16)vals[j];
    }
  }
  __syncthreads();
  char* dst = vtp + ((size_t)(b * 64 + kt)) * TILEB;
#pragma unroll
  for (int i = 0; i < 8; ++i) {
    int c16 = t + i * 256;
    *(bf16x8*)(dst + c16 * 16) = *(const bf16x8*)(lds + c16 * 16);
  }
}

// ---------- main: 4 independent waves x 16q, 2-stage pipeline QK(t+1) || PV(t)
__global__ __launch_bounds__(256) void attn_main(
    const float* __restrict__ qs, const char* __restrict__ kp,
    const char* __restrict__ vtp, const float* __restrict__ scale,
    float* __restrict__ out) {
  extern __shared__ __align__(16) char smem[];
  int b  = blockIdx.x & 7;          // batch -> XCD (L2 locality)
  int qt = blockIdx.x >> 3;
  int tid = threadIdx.x;
  int w = tid >> 6, lane = tid & 63;
  int c = lane & 15, g = lane >> 4;
  int q0 = qt * 64 + w * 16;

  char* kbuf = smem;                // kbuf + (i&1)*TILEB
  char* vbuf = smem + 2 * TILEB;    // vbuf + (i&1)*TILEB
  char* plds = smem + 4 * TILEB + w * 1024;

  float cc = 1.4426950408889634f / scale[0];   // log2(e)/scale folded into Q

  // Q fragments (B-operand for swapped QK; lane holds Q[q=c][k*32+g*8..+7])
  bf16x8 qf[16];
#pragma unroll
  for (int k = 0; k < 16; ++k) {
    int d = k * 32 + g * 8;
    const float4* p = (const float4*)(qs + ((size_t)(b * NSEQ + q0 + c)) * DIM + d);
    float4 x = p[0], y = p[1];
    float vals[8] = {x.x, x.y, x.z, x.w, y.x, y.y, y.z, y.w};
    bf16x8 h;
#pragma unroll
    for (int j = 0; j < 8; ++j) {
      float mlt = (d + j == 0) ? cc : -cc;     // Minkowski sign fold
      h[j] = (__bf16)(vals[j] * mlt);
    }
    qf[k] = h;
  }

  f32x4 acc[32];
#pragma unroll
  for (int i = 0; i < 32; ++i) acc[i] = (f32x4){0.f, 0.f, 0.f, 0.f};
  float mrow = -1e30f;               // running max for q=c (lane-local)

  const char* kpb = kp  + (size_t)b * 64 * TILEB;
  const char* vpb = vtp + (size_t)b * 64 * TILEB;

  const int csw = (c & 7) << 4;                // K swizzle term
  const int vt_lane = (c >> 1) * 128 +
      (((((c & 1) * 64) + g * 16)) ^ (((c >> 1) & 7) << 4));  // V/P A-frag read
  const int qb = (c >> 1) * 128;               // P write-side (q=c per lane)
  const int qh = (c & 1) * 64;
  const int qx = ((c >> 1) & 7) << 4;

  // prologue: stage K(0), V(0), K(1)
#pragma unroll
  for (int i = 0; i < 8; ++i) {
    int o = tid * 16 + i * 4096;
    gld16(kpb + o, kbuf + o);
    gld16(vpb + o, vbuf + o);
    gld16(kpb + TILEB + o, kbuf + TILEB + o);
  }
  __syncthreads();

  f32x4 sl, sh;
  bf16x8 pf;

  // ---- QK(0) + softmax(0) + P(0)
  {
    f32x4 sa0 = {0.f,0.f,0.f,0.f}, sb0 = {0.f,0.f,0.f,0.f};
    f32x4 sa1 = {0.f,0.f,0.f,0.f}, sb1 = {0.f,0.f,0.f,0.f};
    const char* krl = kbuf + c * 1024;
    const char* krh = krl + 16 * 1024;
#pragma unroll
    for (int k = 0; k < 16; ++k) {
      int bir = (k * 64 + g * 16) ^ csw;
      bf16x8 kfl = *(const bf16x8*)(krl + bir);
      bf16x8 kfh = *(const bf16x8*)(krh + bir);
      if (k & 1) {
        sb0 = __builtin_amdgcn_mfma_f32_16x16x32_bf16(kfl, qf[k], sb0, 0, 0, 0);
        sb1 = __builtin_amdgcn_mfma_f32_16x16x32_bf16(kfh, qf[k], sb1, 0, 0, 0);
      } else {
        sa0 = __builtin_amdgcn_mfma_f32_16x16x32_bf16(kfl, qf[k], sa0, 0, 0, 0);
        sa1 = __builtin_amdgcn_mfma_f32_16x16x32_bf16(kfh, qf[k], sa1, 0, 0, 0);
      }
    }
    sl = sa0 + sb0; sh = sa1 + sb1;
    float mm = fmaxf(fmaxf(fmaxf(sl[0], sl[1]), fmaxf(sl[2], sl[3])),
                     fmaxf(fmaxf(sh[0], sh[1]), fmaxf(sh[2], sh[3])));
    mm = fmaxf(mm, __shfl_xor(mm, 16));
    mm = fmaxf(mm, __shfl_xor(mm, 32));
    mrow = mm;                                  // first tile: just set
#pragma unroll
    for (int r = 0; r < 4; ++r) {
      float pvl = exp2f(sl[r] - mrow);
      float pvh = exp2f(sh[r] - mrow);
      int kvl = 4 * g + r;
      *(__bf16*)(plds + qb + ((qh + kvl * 2) ^ qx))        = (__bf16)pvl;
      *(__bf16*)(plds + qb + ((qh + (16 + kvl) * 2) ^ qx)) = (__bf16)pvh;
    }
    pf = *(const bf16x8*)(plds + vt_lane);
  }
  __syncthreads();   // protect kbuf0 (all waves done with QK(0)) before K(2) stage

  // ---- pipelined main loop: iter t does QK(t+1) || PV(t)
  for (int t = 0; t < NKT - 1; ++t) {
    // stage K(t+2) -> kbuf[t&1], V(t+1) -> vbuf[(t+1)&1]  (targets idle since t-1)
    if (t + 2 < NKT) {
      const char* ksrc = kpb + (size_t)(t + 2) * TILEB;
      char* kdst = kbuf + (t & 1) * TILEB;
#pragma unroll
      for (int i = 0; i < 8; ++i) {
        int o = tid * 16 + i * 4096;
        gld16(ksrc + o, kdst + o);
      }
    }
    {
      const char* vsrc = vpb + (size_t)(t + 1) * TILEB;
      char* vdst = vbuf + ((t + 1) & 1) * TILEB;
#pragma unroll
      for (int i = 0; i < 8; ++i) {
        int o = tid * 16 + i * 4096;
        gld16(vsrc + o, vdst + o);
      }
    }

    // ---- merged region: QK(t+1) reads kbuf[(t+1)&1]; PV(t) reads vbuf[t&1]
    f32x4 sa0 = {0.f,0.f,0.f,0.f}, sb0 = {0.f,0.f,0.f,0.f};
    f32x4 sa1 = {0.f,0.f,0.f,0.f}, sb1 = {0.f,0.f,0.f,0.f};
    const char* krl = kbuf + ((t + 1) & 1) * TILEB + c * 1024;
    const char* krh = krl + 16 * 1024;
    const char* vr  = vbuf + (t & 1) * TILEB + vt_lane;
#pragma unroll
    for (int k = 0; k < 16; ++k) {
      int bir = (k * 64 + g * 16) ^ csw;
      bf16x8 kfl = *(const bf16x8*)(krl + bir);
      bf16x8 kfh = *(const bf16x8*)(krh + bir);
      bf16x8 vf0 = *(const bf16x8*)(vr + (2 * k) * 1024);
      bf16x8 vf1 = *(const bf16x8*)(vr + (2 * k + 1) * 1024);
      if (k & 1) {
        sb0 = __builtin_amdgcn_mfma_f32_16x16x32_bf16(kfl, qf[k], sb0, 0, 0, 0);
        sb1 = __builtin_amdgcn_mfma_f32_16x16x32_bf16(kfh, qf[k], sb1, 0, 0, 0);
      } else {
        sa0 = __builtin_amdgcn_mfma_f32_16x16x32_bf16(kfl, qf[k], sa0, 0, 0, 0);
        sa1 = __builtin_amdgcn_mfma_f32_16x16x32_bf16(kfh, qf[k], sa1, 0, 0, 0);
      }
      acc[2 * k]     = __builtin_amdgcn_mfma_f32_16x16x32_bf16(pf, vf0, acc[2 * k], 0, 0, 0);
      acc[2 * k + 1] = __builtin_amdgcn_mfma_f32_16x16x32_bf16(pf, vf1, acc[2 * k + 1], 0, 0, 0);
    }
    sl = sa0 + sb0; sh = sa1 + sb1;

    // ---- softmax(t+1) (lane-local row q=c; reduce over g only)
    float mm = fmaxf(fmaxf(fmaxf(sl[0], sl[1]), fmaxf(sl[2], sl[3])),
                     fmaxf(fmaxf(sh[0], sh[1]), fmaxf(sh[2], sh[3])));
    mm = fmaxf(mm, __shfl_xor(mm, 16));
    mm = fmaxf(mm, __shfl_xor(mm, 32));
    if (__any(mm > mrow + 11.0f)) {          // defer-max (2^11 headroom)
      float mn = fmaxf(mrow, mm);
      float f = exp2f(mrow - mn);
      mrow = mn;
      float f0 = __shfl(f, 4 * g + 0), f1 = __shfl(f, 4 * g + 1);
      float f2 = __shfl(f, 4 * g + 2), f3 = __shfl(f, 4 * g + 3);
#pragma unroll
      for (int i = 0; i < 32; ++i) {
        acc[i][0] *= f0; acc[i][1] *= f1; acc[i][2] *= f2; acc[i][3] *= f3;
      }
    }

    // ---- P(t+1) write + A-frag read (per-wave LDS, no barrier needed)
#pragma unroll
    for (int r = 0; r < 4; ++r) {
      float pvl = exp2f(sl[r] - mrow);
      float pvh = exp2f(sh[r] - mrow);
      int kvl = 4 * g + r;
      *(__bf16*)(plds + qb + ((qh + kvl * 2) ^ qx))        = (__bf16)pvl;
      *(__bf16*)(plds + qb + ((qh + (16 + kvl) * 2) ^ qx)) = (__bf16)pvh;
    }
    pf = *(const bf16x8*)(plds + vt_lane);

    __syncthreads();   // drain stages; all waves done reading this iter's buffers
  }

  // ---- tail: PV(NKT-1)
  {
    const char* vr = vbuf + ((NKT - 1) & 1) * TILEB + vt_lane;
#pragma unroll
    for (int dtl = 0; dtl < 32; ++dtl) {
      bf16x8 vf = *(const bf16x8*)(vr + dtl * 1024);
      acc[dtl] = __builtin_amdgcn_mfma_f32_16x16x32_bf16(pf, vf, acc[dtl], 0, 0, 0);
    }
  }

  // ---- epilogue: Lorentz normalization (softmax denom cancels; EPS preserved)
#pragma unroll
  for (int r = 0; r < 4; ++r) {
    float ss = 0.f;
#pragma unroll
    for (int dtl = 0; dtl < 32; ++dtl) ss += acc[dtl][r] * acc[dtl][r];
    ss += __shfl_xor(ss, 1);
    ss += __shfl_xor(ss, 2);
    ss += __shfl_xor(ss, 4);
    ss += __shfl_xor(ss, 8);
    float a0 = __shfl(acc[0][r], lane & 48);   // lane c==0 holds O[q][0]
    float d2 = fabsf(2.f * a0 * a0 - ss);
    float inv = rsqrtf(fmaxf(d2, 1e-8f));
    float* orow = out + ((size_t)(b * NSEQ + q0 + 4 * g + r)) * DIM + c;
#pragma unroll
    for (int dtl = 0; dtl < 32; ++dtl) orow[dtl * 16] = acc[dtl][r] * inv;
  }
}

extern "C" void kernel_launch(void* const* d_in, const int* in_sizes, int n_in,
                              void* d_out, int out_size, void* d_ws, size_t ws_size,
                              hipStream_t stream) {
  (void)in_sizes; (void)n_in; (void)out_size;
  const float* qs = (const float*)d_in[0];
  const float* ks = (const float*)d_in[1];
  const float* vs = (const float*)d_in[2];
  const float* scale = (const float*)d_in[3];
  // d_in[4] (bias) is uniform across softmax axis -> invariant -> unused
  float* out = (float*)d_out;

  size_t need = (size_t)2 * 8 * 64 * TILEB;   // 33.5 MB
  if (ws_size < need) return;
  char* kp  = (char*)d_ws;
  char* vtp = (char*)d_ws + (size_t)8 * 64 * TILEB;

  hipFuncSetAttribute((const void*)attn_main,
                      hipFuncAttributeMaxDynamicSharedMemorySize, SMEMB);

  prep_k<<<512, 256, 0, stream>>>(ks, kp);
  prep_v<<<512, 256, 0, stream>>>(vs, vtp);
  attn_main<<<256, 256, SMEMB, stream>>>(qs, kp, vtp, scale, out);
}